// Round 13
// baseline (373.465 us; speedup 1.0000x reference)
//
#include <hip/hip_runtime.h>
#include <hip/hip_bf16.h>

namespace {
constexpr int S = 2048;
constexpr int D = 64;
constexpr float QSCALE = 0.18033688011112042f;  // (1/sqrt(64)) * log2(e)

using f32x4 = __attribute__((ext_vector_type(4))) float;
using bf16x8 = __attribute__((ext_vector_type(8))) short;

__device__ __forceinline__ short f2bf(float f) {
  return __builtin_bit_cast(short, __float2bfloat16(f));  // native RNE cvt
}
#if __has_builtin(__builtin_amdgcn_exp2f)
__device__ __forceinline__ float exp2_fast(float x) { return __builtin_amdgcn_exp2f(x); }
#else
__device__ __forceinline__ float exp2_fast(float x) { return exp2f(x); }
#endif

__device__ __forceinline__ void bar_lds() {  // lgkm-only barrier: vmem prefetch stays in flight
  asm volatile("s_waitcnt lgkmcnt(0)" ::: "memory");
  __builtin_amdgcn_s_barrier();
}
}  // namespace

// One block = (bh, 64 q-rows). Phase-rebalanced:
//   zero-fill first (stores overlap everyone's compute),
//   loop A (LEAN): K-only staging, QK+exp -> l.   No PV, no V, no pscr.
//   loop B (FAT):  K+V staging, QK+exp -> normalized-a NT store + pscr -> PV.
// B is store-backpressure-bound, so its extra compute is free; A's store-starved
// window shrinks ~40%. 40KB LDS -> 4 blocks/CU.
__global__ __launch_bounds__(256, 4) void attn_fused(const float* __restrict__ qg,
                                                     const float* __restrict__ kg,
                                                     const float* __restrict__ vg,
                                                     float* __restrict__ outg) {
  __shared__ short kbuf[2][64 * 64];   // K[j][d] bf16, XOR-swizzled, dbuf
  __shared__ short vbuf[2][64 * 64];   // V^T[d][j] bf16, XOR-swizzled, dbuf
  __shared__ short pscr[4][16 * 64];   // per-wave p~ redistribution scratch (B only)

  const int tid = threadIdx.x;
  const int w = tid >> 6, lane = tid & 63, lg = lane >> 4, lr = lane & 15;

  // XCD-chunked block map + long/short qt interleave for co-resident balance
  const int u = blockIdx.x;
  const int logical = (u & 7) * 256 + (u >> 3);  // 2048 % 8 == 0
  const int bh = logical >> 5;
  const int uu = logical & 31;
  const int qt = (uu & 1) ? (31 - (uu >> 1)) : (uu >> 1);
  const int qrow0 = qt * 64;
  const int NT = qt + 1;

  const size_t bh_off = (size_t)bh * S * D;
  float* const og = outg;
  float* const a_base = outg + (size_t)64 * S * D + (size_t)bh * S * S;
  const int asw = (lr & 7) << 3;

  const int igl = qrow0 + w * 16 + lr;  // this lane's q-row (QK col i / p row)

  const int krow = tid >> 2, kc = (tid & 3) * 16;
  const int kswz = (krow & 7) << 3;
  const int vj = tid & 63, vd0 = (tid >> 6) * 16;

  f32x4 ka[4], va[4];

#define LOAD_K(kt_) do { const float* kp_ = kg + bh_off + (size_t)((kt_) * 64 + krow) * D + kc; \
    ka[0] = *(const f32x4*)(kp_);     ka[1] = *(const f32x4*)(kp_ + 4);                         \
    ka[2] = *(const f32x4*)(kp_ + 8); ka[3] = *(const f32x4*)(kp_ + 12); } while (0)
#define LOAD_V(kt_) do { const float* vp_ = vg + bh_off + (size_t)((kt_) * 64 + vj) * D + vd0;  \
    va[0] = *(const f32x4*)(vp_);     va[1] = *(const f32x4*)(vp_ + 4);                         \
    va[2] = *(const f32x4*)(vp_ + 8); va[3] = *(const f32x4*)(vp_ + 12); } while (0)
#define STAGE_K(buf_) do { bf16x8 kb_;                                                           \
    _Pragma("unroll") for (int e = 0; e < 4; ++e) { kb_[e] = f2bf(ka[0][e]); kb_[e+4] = f2bf(ka[1][e]); } \
    *(bf16x8*)(&kbuf[buf_][(krow * 64 + kc) ^ kswz]) = kb_;                                      \
    _Pragma("unroll") for (int e = 0; e < 4; ++e) { kb_[e] = f2bf(ka[2][e]); kb_[e+4] = f2bf(ka[3][e]); } \
    *(bf16x8*)(&kbuf[buf_][(krow * 64 + kc + 8) ^ kswz]) = kb_; } while (0)
#define STAGE_V(buf_) do {                                                                       \
    _Pragma("unroll") for (int i = 0; i < 4; ++i)                                                \
    _Pragma("unroll") for (int e = 0; e < 4; ++e) {                                              \
      const int d_ = vd0 + i * 4 + e;                                                            \
      vbuf[buf_][(d_ * 64 + vj) ^ ((d_ & 7) << 3)] = f2bf(va[i][e]); } } while (0)

  // ---- issue tile-0 K load BEFORE the zero-fill store burst (latency hides) ----
  LOAD_K(0);

  // ---- zero tiles (j >= NT*64) FIRST: fire-and-forget NT stores ----
  {
    float* const arow = a_base + (size_t)igl * S;
    const f32x4 z = {0.f, 0.f, 0.f, 0.f};
    for (int zt = NT; zt < S / 64; ++zt) {
#pragma unroll
      for (int jb = 0; jb < 4; ++jb)
        __builtin_nontemporal_store(z, (f32x4*)(arow + zt * 64 + jb * 16 + lg * 4));
    }
  }

  // ---- Q B-fragment (col i = lane's row, k = d), QSCALE folded ----
  bf16x8 qf[2];
#pragma unroll
  for (int kh = 0; kh < 2; ++kh) {
    const float* qp = qg + bh_off + (size_t)igl * D + kh * 32 + lg * 8;
    f32x4 x0 = *(const f32x4*)(qp);
    f32x4 x1 = *(const f32x4*)(qp + 4);
    bf16x8 f;
#pragma unroll
    for (int e = 0; e < 4; ++e) {
      f[e] = f2bf(x0[e] * QSCALE);
      f[e + 4] = f2bf(x1[e] * QSCALE);
    }
    qf[kh] = f;
  }

  // ================= loop A (lean): K-only, QK + exp -> l =================
  STAGE_K(0);
  bar_lds();

  float l_acc = 0.f;
  for (int kt = 0; kt < NT; ++kt) {
    const int cur = kt & 1;
    if (kt + 1 < NT) LOAD_K(kt + 1);  // prefetch next K tile into regs

    f32x4 sacc[4];
#pragma unroll
    for (int jb = 0; jb < 4; ++jb) sacc[jb] = (f32x4){0.f, 0.f, 0.f, 0.f};
#pragma unroll
    for (int kh = 0; kh < 2; ++kh) {
#pragma unroll
      for (int jb = 0; jb < 4; ++jb) {
        bf16x8 kf = *(const bf16x8*)(&kbuf[cur][((jb * 16 + lr) * 64 + kh * 32 + lg * 8) ^ asw]);
        sacc[jb] = __builtin_amdgcn_mfma_f32_16x16x32_bf16(kf, qf[kh], sacc[jb], 0, 0, 0);
      }
    }

    const bool diag = (kt == NT - 1);
#pragma unroll
    for (int jb = 0; jb < 4; ++jb) {
#pragma unroll
      for (int r = 0; r < 4; ++r) {
        const int jgl = kt * 64 + jb * 16 + lg * 4 + r;
        float pt = exp2_fast(sacc[jb][r]);
        if (diag && jgl > igl) pt = 0.f;
        l_acc += pt;
      }
    }

    if (kt + 1 < NT) STAGE_K(cur ^ 1);
    bar_lds();
  }

  // ---- rl: reduce partials across lg; bounce to get O-row-aligned copies ----
  l_acc += __shfl_xor(l_acc, 16, 64);
  l_acc += __shfl_xor(l_acc, 32, 64);
  const float rlA = 1.f / l_acc;  // rl for row igl (a-store path)
  float rr[4];                    // rl at rows w*16+lg*4+r (O path), held through B
  {
    float* const rlv = (float*)(&pscr[w][0]);
    if (lane < 16) rlv[lr] = rlA;
    asm volatile("s_waitcnt lgkmcnt(0)" ::: "memory");  // same-wave write->read
#pragma unroll
    for (int r = 0; r < 4; ++r) rr[r] = rlv[lg * 4 + r];
  }

  // ========== loop B (fat): K+V, QK + exp -> a store + pscr -> PV ==========
  float* const arow = a_base + (size_t)igl * S;
  f32x4 oacc[4];
#pragma unroll
  for (int dg = 0; dg < 4; ++dg) oacc[dg] = (f32x4){0.f, 0.f, 0.f, 0.f};

  LOAD_K(0);
  LOAD_V(0);
  STAGE_K(0);
  STAGE_V(0);
  bar_lds();

  for (int kt = 0; kt < NT; ++kt) {
    const int cur = kt & 1;
    if (kt + 1 < NT) {  // prefetch next K/V tiles into regs
      LOAD_K(kt + 1);
      LOAD_V(kt + 1);
    }

    f32x4 sacc[4];
#pragma unroll
    for (int jb = 0; jb < 4; ++jb) sacc[jb] = (f32x4){0.f, 0.f, 0.f, 0.f};
#pragma unroll
    for (int kh = 0; kh < 2; ++kh) {
#pragma unroll
      for (int jb = 0; jb < 4; ++jb) {
        bf16x8 kf = *(const bf16x8*)(&kbuf[cur][((jb * 16 + lr) * 64 + kh * 32 + lg * 8) ^ asw]);
        sacc[jb] = __builtin_amdgcn_mfma_f32_16x16x32_bf16(kf, qf[kh], sacc[jb], 0, 0, 0);
      }
    }

    // exp -> normalized-a NT store (earliest possible) + bf16 p~ -> pscr
    const bool diag = (kt == NT - 1);
#pragma unroll
    for (int jb = 0; jb < 4; ++jb) {
      f32x4 av;
      short4 ps;
#pragma unroll
      for (int r = 0; r < 4; ++r) {
        const int jgl = kt * 64 + jb * 16 + lg * 4 + r;
        float pt = exp2_fast(sacc[jb][r]);
        if (diag && jgl > igl) pt = 0.f;
        av[r] = pt * rlA;
        ((short*)&ps)[r] = f2bf(pt);
      }
      __builtin_nontemporal_store(av, (f32x4*)(arow + kt * 64 + jb * 16 + lg * 4));
      *(short4*)(&pscr[w][(lr * 64 + jb * 16 + lg * 4) ^ asw]) = ps;
    }

    // PV: O[i][d] += p~ V (pscr same-wave; compiler inserts the lgkm wait)
#pragma unroll
    for (int ks = 0; ks < 2; ++ks) {
      bf16x8 pa = *(const bf16x8*)(&pscr[w][(lr * 64 + ks * 32 + lg * 8) ^ asw]);
#pragma unroll
      for (int dg = 0; dg < 4; ++dg) {
        bf16x8 vb = *(const bf16x8*)(&vbuf[cur][((dg * 16 + lr) * 64 + ks * 32 + lg * 8) ^ asw]);
        oacc[dg] = __builtin_amdgcn_mfma_f32_16x16x32_bf16(pa, vb, oacc[dg], 0, 0, 0);
      }
    }

    if (kt + 1 < NT) {  // stage next tiles into the other buffers
      STAGE_K(cur ^ 1);
      STAGE_V(cur ^ 1);
    }
    bar_lds();
  }

  // ---- O write: lane holds O[i=w*16+lg*4+r][d=dg*16+lr]; rr from the A-phase bounce ----
#pragma unroll
  for (int dg = 0; dg < 4; ++dg) {
#pragma unroll
    for (int r = 0; r < 4; ++r) {
      const int il = qrow0 + w * 16 + lg * 4 + r;
      og[bh_off + (size_t)il * D + dg * 16 + lr] = oacc[dg][r] * rr[r];
    }
  }

#undef LOAD_K
#undef LOAD_V
#undef STAGE_K
#undef STAGE_V
}

extern "C" void kernel_launch(void* const* d_in, const int* in_sizes, int n_in,
                              void* d_out, int out_size, void* d_ws, size_t ws_size,
                              hipStream_t stream) {
  const float* q = (const float*)d_in[0];
  const float* k = (const float*)d_in[1];
  const float* v = (const float*)d_in[2];
  float* out = (float*)d_out;
  attn_fused<<<dim3(2048), dim3(256), 0, stream>>>(q, k, v, out);
}